// Round 1
// baseline (486.241 us; speedup 1.0000x reference)
//
#include <hip/hip_runtime.h>
#include <stdint.h>

typedef float  f32x4  __attribute__((ext_vector_type(4)));
typedef short  s16x8  __attribute__((ext_vector_type(8)));
typedef unsigned int u32x4 __attribute__((ext_vector_type(4)));
typedef unsigned short ushort_t;

#define B_  4
#define S_  2048
#define E_  2048
#define DH_ 256

#define MFMA16(a,b,c) __builtin_amdgcn_mfma_f32_16x16x32_bf16((a),(b),(c),0,0,0)

__device__ __forceinline__ ushort_t f2b(float f){
  unsigned u = __builtin_bit_cast(unsigned, f);
  u += 0x7fffu + ((u >> 16) & 1u);   // RNE
  return (ushort_t)(u >> 16);
}

// ---------------- x fp32 -> bf16 ----------------
__global__ __launch_bounds__(256) void k_convert_x(const float* __restrict__ x,
                                                   ushort_t* __restrict__ xbf){
  size_t i = ((size_t)blockIdx.x * 256 + threadIdx.x) * 8;
  f32x4 a = *(const f32x4*)(x + i);
  f32x4 b = *(const f32x4*)(x + i + 4);
  union { ushort_t us[8]; u32x4 v; } u;
#pragma unroll
  for (int j = 0; j < 4; ++j){ u.us[j] = f2b(a[j]); u.us[4+j] = f2b(b[j]); }
  *(u32x4*)(xbf + i) = u.v;
}

// ---------------- W[2048][256] -> Wt bf16 [3][256][2048] ----------------
__global__ __launch_bounds__(256) void k_transpose_w(const float* __restrict__ Wq,
                                                     const float* __restrict__ Wk,
                                                     const float* __restrict__ Wv,
                                                     ushort_t* __restrict__ Wt){
  __shared__ ushort_t tile[32][33];
  int z = blockIdx.z;
  const float* W = (z == 0) ? Wq : ((z == 1) ? Wk : Wv);
  int k0 = blockIdx.x * 32, n0 = blockIdx.y * 32;
  int t = threadIdx.x, tx = t & 31, ty = t >> 5;
#pragma unroll
  for (int i = 0; i < 4; ++i)
    tile[ty + i*8][tx] = f2b(W[(size_t)(k0 + ty + i*8) * DH_ + n0 + tx]);
  __syncthreads();
#pragma unroll
  for (int i = 0; i < 4; ++i)
    Wt[(size_t)z * DH_ * E_ + (size_t)(n0 + ty + i*8) * E_ + k0 + tx] = tile[tx][ty + i*8];
}

// ---------------- padding mask (bool-bytes OR int32) -> float 0/-inf ----------------
__global__ __launch_bounds__(256) void k_prep_pad(const unsigned char* __restrict__ pm,
                                                  float* __restrict__ padf){
  const int n = B_ * S_;
  int any = 0;
  for (int i = threadIdx.x; i < n; i += 256)
    if ((i & 3) && pm[i]) any = 1;            // nonzero at i%4!=0 => bool layout
  int isb = __syncthreads_or(any);
  for (int i = threadIdx.x; i < n; i += 256){
    unsigned char v = isb ? pm[i] : pm[(size_t)i * 4];
    padf[i] = v ? -__builtin_inff() : 0.0f;
  }
}

// ---------------- QKV projection GEMM: [8192,2048] x [2048,256] (bf16 MFMA) ----------------
__global__ __launch_bounds__(256) void k_gemm_qkv(const ushort_t* __restrict__ xbf,
                                                  const ushort_t* __restrict__ Wt,
                                                  const float* __restrict__ bQ,
                                                  const float* __restrict__ bK,
                                                  const float* __restrict__ bV,
                                                  ushort_t* __restrict__ Qo,
                                                  ushort_t* __restrict__ Ko,
                                                  ushort_t* __restrict__ Vo){
  // LDS tiles: 64 rows x 64 k-elems (bf16), row stride 128B, XOR swizzle (row&7)<<4
  __shared__ __align__(16) ushort_t Al[64 * 64];
  __shared__ __align__(16) ushort_t Bl[64 * 64];
  int z = blockIdx.z;
  const ushort_t* W = Wt + (size_t)z * DH_ * E_;
  const float* bias = (z == 0) ? bQ : ((z == 1) ? bK : bV);
  ushort_t* out = (z == 0) ? Qo : ((z == 1) ? Ko : Vo);
  int m0 = blockIdx.x * 64, n0 = blockIdx.y * 64;
  int t = threadIdx.x;
  int lane = t & 63, w = t >> 6, lo = lane & 15, grp = lane >> 4;
  f32x4 z4; z4[0] = z4[1] = z4[2] = z4[3] = 0.f;
  f32x4 acc[4] = { z4, z4, z4, z4 };
  int arow = t >> 2;
  int c8a  = t & 3;

  for (int k0 = 0; k0 < E_; k0 += 64){
    __syncthreads();
#pragma unroll
    for (int p = 0; p < 2; ++p){
      int c8 = c8a + p * 4;
      u32x4 av = *(const u32x4*)(xbf + (size_t)(m0 + arow) * E_ + k0 + c8 * 8);
      *(u32x4*)((char*)Al + ((arow * 128 + c8 * 16) ^ ((arow & 7) << 4))) = av;
      u32x4 bv = *(const u32x4*)(W + (size_t)(n0 + arow) * E_ + k0 + c8 * 8);
      *(u32x4*)((char*)Bl + ((arow * 128 + c8 * 16) ^ ((arow & 7) << 4))) = bv;
    }
    __syncthreads();
#pragma unroll
    for (int kk = 0; kk < 2; ++kk){
      int ar = w * 16 + lo;
      s16x8 a = *(const s16x8*)((const char*)Al +
                 ((ar * 128 + kk * 64 + grp * 16) ^ ((ar & 7) << 4)));
#pragma unroll
      for (int nt = 0; nt < 4; ++nt){
        int br = nt * 16 + lo;
        s16x8 b = *(const s16x8*)((const char*)Bl +
                   ((br * 128 + kk * 64 + grp * 16) ^ ((br & 7) << 4)));
        acc[nt] = MFMA16(a, b, acc[nt]);
      }
    }
  }
#pragma unroll
  for (int nt = 0; nt < 4; ++nt){
    int col = n0 + nt * 16 + lo;
    float bb = bias[col];
#pragma unroll
    for (int r = 0; r < 4; ++r){
      int row = m0 + w * 16 + grp * 4 + r;
      out[(size_t)row * DH_ + col] = f2b(acc[nt][r] + bb);
    }
  }
}

// ---------------- V[8192][256] -> Vt bf16 [4][256][2048] ----------------
__global__ __launch_bounds__(256) void k_transpose_v(const ushort_t* __restrict__ V,
                                                     ushort_t* __restrict__ Vt){
  __shared__ ushort_t tile[32][33];
  int r0 = blockIdx.x * 32, c0 = blockIdx.y * 32;
  int t = threadIdx.x, tx = t & 31, ty = t >> 5;
#pragma unroll
  for (int i = 0; i < 4; ++i)
    tile[ty + i*8][tx] = V[(size_t)(r0 + ty + i*8) * DH_ + c0 + tx];
  __syncthreads();
  int b = r0 >> 11, s0 = r0 & (S_ - 1);
#pragma unroll
  for (int i = 0; i < 4; ++i)
    Vt[(size_t)(b * DH_ + c0 + ty + i*8) * S_ + s0 + tx] = tile[tx][ty + i*8];
}

// ---------------- flash attention: 1 wave = 16 q rows ----------------
__global__ __launch_bounds__(64) void k_attn(const ushort_t* __restrict__ Q,
                                             const ushort_t* __restrict__ K,
                                             const ushort_t* __restrict__ Vt,
                                             const float* __restrict__ padf,
                                             float* __restrict__ out){
  __shared__ __align__(16) ushort_t P[16][32];
  int blk = blockIdx.x;
  int b = blk & (B_ - 1);
  int qt = (S_ / 16 - 1) - (blk >> 2);          // deepest q-tiles launch first
  int lane = threadIdx.x, lo = lane & 15, grp = lane >> 4;
  int qbase = qt * 16;
  const float NEG = -__builtin_inff();

  s16x8 aq[8];
#pragma unroll
  for (int d = 0; d < 8; ++d)
    aq[d] = *(const s16x8*)(Q + (size_t)(b * S_ + qbase + lo) * DH_ + d * 32 + grp * 8);

  f32x4 z4; z4[0] = z4[1] = z4[2] = z4[3] = 0.f;
  f32x4 o[16];
#pragma unroll
  for (int t = 0; t < 16; ++t) o[t] = z4;
  float m[4], l[4];
#pragma unroll
  for (int r = 0; r < 4; ++r){ m[r] = NEG; l[r] = 0.f; }

  int qhi = qbase + 15;
  int ntiles = (qhi >> 5) + 1;

  for (int kt = 0; kt < ntiles; ++kt){
    int k0 = kt * 32;
    f32x4 s[2];
#pragma unroll
    for (int h = 0; h < 2; ++h){
      int kb = k0 + h * 16;
      if (kb <= qhi){
        f32x4 acc = z4;
#pragma unroll
        for (int d = 0; d < 8; ++d){
          s16x8 bk = *(const s16x8*)(K + (size_t)(b * S_ + kb + lo) * DH_ + d * 32 + grp * 8);
          acc = MFMA16(aq[d], bk, acc);
        }
        int kcol = kb + lo;
        float pv = padf[b * S_ + kcol];
#pragma unroll
        for (int r = 0; r < 4; ++r){
          int q = qbase + grp * 4 + r;
          float v = acc[r] * 0.0625f + pv;     // 1/sqrt(256)
          s[h][r] = (kcol <= q) ? v : NEG;
        }
      } else {
#pragma unroll
        for (int r = 0; r < 4; ++r) s[h][r] = NEG;
      }
    }
    // online softmax (rows live on lane groups of 16; reduce over low 4 lane bits)
    float alpha[4];
    int need = 0;
#pragma unroll
    for (int r = 0; r < 4; ++r){
      float mr = fmaxf(s[0][r], s[1][r]);
      mr = fmaxf(mr, __shfl_xor(mr, 1));
      mr = fmaxf(mr, __shfl_xor(mr, 2));
      mr = fmaxf(mr, __shfl_xor(mr, 4));
      mr = fmaxf(mr, __shfl_xor(mr, 8));
      float mn = fmaxf(m[r], mr);
      float al = __expf(m[r] - mn);
      alpha[r] = al;
      float p0 = __expf(s[0][r] - mn);
      float p1 = __expf(s[1][r] - mn);
      s[0][r] = p0; s[1][r] = p1;
      float pr = p0 + p1;
      pr += __shfl_xor(pr, 1);
      pr += __shfl_xor(pr, 2);
      pr += __shfl_xor(pr, 4);
      pr += __shfl_xor(pr, 8);
      l[r] = l[r] * al + pr;
      need |= (mn > m[r]);
      m[r] = mn;
    }
    if (__any(need)){
#pragma unroll
      for (int t = 0; t < 16; ++t)
#pragma unroll
        for (int r = 0; r < 4; ++r) o[t][r] *= alpha[r];
    }
    // P -> LDS (bf16), re-fragment as MFMA A operand
#pragma unroll
    for (int h = 0; h < 2; ++h)
#pragma unroll
      for (int r = 0; r < 4; ++r)
        P[grp * 4 + r][h * 16 + lo] = f2b(s[h][r]);
    s16x8 pa = *(const s16x8*)(&P[lo][grp * 8]);
#pragma unroll
    for (int t = 0; t < 16; ++t){
      s16x8 vb = *(const s16x8*)(Vt + (size_t)(b * DH_ + t * 16 + lo) * S_ + k0 + grp * 8);
      o[t] = MFMA16(pa, vb, o[t]);
    }
  }
  float linv[4];
#pragma unroll
  for (int r = 0; r < 4; ++r) linv[r] = 1.0f / l[r];
#pragma unroll
  for (int t = 0; t < 16; ++t)
#pragma unroll
    for (int r = 0; r < 4; ++r)
      out[(size_t)(b * S_ + qbase + grp * 4 + r) * DH_ + t * 16 + lo] = o[t][r] * linv[r];
}

extern "C" void kernel_launch(void* const* d_in, const int* in_sizes, int n_in,
                              void* d_out, int out_size, void* d_ws, size_t ws_size,
                              hipStream_t stream){
  const float* x          = (const float*)d_in[0];
  // d_in[1] = causal_mask (semantics fixed: lower-triangular) — not read
  const unsigned char* pm = (const unsigned char*)d_in[2];
  const float* Wq = (const float*)d_in[3];
  const float* bQ = (const float*)d_in[4];
  const float* Wk = (const float*)d_in[5];
  const float* bK = (const float*)d_in[6];
  const float* Wv = (const float*)d_in[7];
  const float* bV = (const float*)d_in[8];
  float* out = (float*)d_out;

  char* ws = (char*)d_ws;
  ushort_t* xbf  = (ushort_t*)(ws);              // 33,554,432 B
  ushort_t* Wt   = (ushort_t*)(ws + 33554432);   //  3,145,728 B
  ushort_t* Qb   = (ushort_t*)(ws + 36700160);   //  4,194,304 B
  ushort_t* Kb   = (ushort_t*)(ws + 40894464);   //  4,194,304 B
  ushort_t* Vb   = (ushort_t*)(ws + 45088768);   //  4,194,304 B
  ushort_t* Vt   = (ushort_t*)(ws + 49283072);   //  4,194,304 B
  float*    padf = (float*)  (ws + 53477376);    //     32,768 B  (total ~53.5 MB)

  k_convert_x  <<<dim3(8192),       dim3(256), 0, stream>>>(x, xbf);
  k_transpose_w<<<dim3(64, 8, 3),   dim3(256), 0, stream>>>(Wq, Wk, Wv, Wt);
  k_prep_pad   <<<dim3(1),          dim3(256), 0, stream>>>(pm, padf);
  k_gemm_qkv   <<<dim3(128, 4, 3),  dim3(256), 0, stream>>>(xbf, Wt, bQ, bK, bV, Qb, Kb, Vb);
  k_transpose_v<<<dim3(256, 8),     dim3(256), 0, stream>>>(Vb, Vt);
  k_attn       <<<dim3(512),        dim3(64),  0, stream>>>(Qb, Kb, Vt, padf, out);
}

// Round 2
// 300.417 us; speedup vs baseline: 1.6186x; 1.6186x over previous
//
#include <hip/hip_runtime.h>
#include <stdint.h>

typedef float  f32x4  __attribute__((ext_vector_type(4)));
typedef short  s16x8  __attribute__((ext_vector_type(8)));
typedef unsigned int u32x4 __attribute__((ext_vector_type(4)));
typedef unsigned short ushort_t;

#define B_  4
#define S_  2048
#define E_  2048
#define DH_ 256

#define MFMA16(a,b,c) __builtin_amdgcn_mfma_f32_16x16x32_bf16((a),(b),(c),0,0,0)

__device__ __forceinline__ ushort_t f2b(float f){
  unsigned u = __builtin_bit_cast(unsigned, f);
  u += 0x7fffu + ((u >> 16) & 1u);   // RNE
  return (ushort_t)(u >> 16);
}

// ---------------- x fp32 -> bf16 ----------------
__global__ __launch_bounds__(256) void k_convert_x(const float* __restrict__ x,
                                                   ushort_t* __restrict__ xbf){
  size_t i = ((size_t)blockIdx.x * 256 + threadIdx.x) * 8;
  f32x4 a = *(const f32x4*)(x + i);
  f32x4 b = *(const f32x4*)(x + i + 4);
  union { ushort_t us[8]; u32x4 v; } u;
#pragma unroll
  for (int j = 0; j < 4; ++j){ u.us[j] = f2b(a[j]); u.us[4+j] = f2b(b[j]); }
  *(u32x4*)(xbf + i) = u.v;
}

// ---------------- W[2048][256] -> Wt bf16 [3][256][2048] ----------------
__global__ __launch_bounds__(256) void k_transpose_w(const float* __restrict__ Wq,
                                                     const float* __restrict__ Wk,
                                                     const float* __restrict__ Wv,
                                                     ushort_t* __restrict__ Wt){
  __shared__ ushort_t tile[32][33];
  int z = blockIdx.z;
  const float* W = (z == 0) ? Wq : ((z == 1) ? Wk : Wv);
  int k0 = blockIdx.x * 32, n0 = blockIdx.y * 32;
  int t = threadIdx.x, tx = t & 31, ty = t >> 5;
#pragma unroll
  for (int i = 0; i < 4; ++i)
    tile[ty + i*8][tx] = f2b(W[(size_t)(k0 + ty + i*8) * DH_ + n0 + tx]);
  __syncthreads();
#pragma unroll
  for (int i = 0; i < 4; ++i)
    Wt[(size_t)z * DH_ * E_ + (size_t)(n0 + ty + i*8) * E_ + k0 + tx] = tile[tx][ty + i*8];
}

// ---------------- padding mask (bool-bytes OR int32) -> float 0/-inf ----------------
__global__ __launch_bounds__(256) void k_prep_pad(const unsigned char* __restrict__ pm,
                                                  float* __restrict__ padf){
  const int n = B_ * S_;
  int any = 0;
  for (int i = threadIdx.x; i < n; i += 256)
    if ((i & 3) && pm[i]) any = 1;            // nonzero at i%4!=0 => bool layout
  int isb = __syncthreads_or(any);
  for (int i = threadIdx.x; i < n; i += 256){
    unsigned char v = isb ? pm[i] : pm[(size_t)i * 4];
    padf[i] = v ? -__builtin_inff() : 0.0f;
  }
}

// ---------------- QKV projection GEMM: [8192,2048] x [2048,256] (bf16 MFMA) ----------------
__global__ __launch_bounds__(256) void k_gemm_qkv(const ushort_t* __restrict__ xbf,
                                                  const ushort_t* __restrict__ Wt,
                                                  const float* __restrict__ bQ,
                                                  const float* __restrict__ bK,
                                                  const float* __restrict__ bV,
                                                  ushort_t* __restrict__ Qo,
                                                  ushort_t* __restrict__ Ko,
                                                  ushort_t* __restrict__ Vo){
  __shared__ __align__(16) ushort_t Al[64 * 64];
  __shared__ __align__(16) ushort_t Bl[64 * 64];
  int z = blockIdx.z;
  const ushort_t* W = Wt + (size_t)z * DH_ * E_;
  const float* bias = (z == 0) ? bQ : ((z == 1) ? bK : bV);
  ushort_t* out = (z == 0) ? Qo : ((z == 1) ? Ko : Vo);
  int m0 = blockIdx.x * 64, n0 = blockIdx.y * 64;
  int t = threadIdx.x;
  int lane = t & 63, w = t >> 6, lo = lane & 15, grp = lane >> 4;
  f32x4 z4; z4[0] = z4[1] = z4[2] = z4[3] = 0.f;
  f32x4 acc[4] = { z4, z4, z4, z4 };
  int arow = t >> 2;
  int c8a  = t & 3;

  for (int k0 = 0; k0 < E_; k0 += 64){
    __syncthreads();
#pragma unroll
    for (int p = 0; p < 2; ++p){
      int c8 = c8a + p * 4;
      u32x4 av = *(const u32x4*)(xbf + (size_t)(m0 + arow) * E_ + k0 + c8 * 8);
      *(u32x4*)((char*)Al + ((arow * 128 + c8 * 16) ^ ((arow & 7) << 4))) = av;
      u32x4 bv = *(const u32x4*)(W + (size_t)(n0 + arow) * E_ + k0 + c8 * 8);
      *(u32x4*)((char*)Bl + ((arow * 128 + c8 * 16) ^ ((arow & 7) << 4))) = bv;
    }
    __syncthreads();
#pragma unroll
    for (int kk = 0; kk < 2; ++kk){
      int ar = w * 16 + lo;
      s16x8 a = *(const s16x8*)((const char*)Al +
                 ((ar * 128 + kk * 64 + grp * 16) ^ ((ar & 7) << 4)));
#pragma unroll
      for (int nt = 0; nt < 4; ++nt){
        int br = nt * 16 + lo;
        s16x8 b = *(const s16x8*)((const char*)Bl +
                   ((br * 128 + kk * 64 + grp * 16) ^ ((br & 7) << 4)));
        acc[nt] = MFMA16(a, b, acc[nt]);
      }
    }
  }
#pragma unroll
  for (int nt = 0; nt < 4; ++nt){
    int col = n0 + nt * 16 + lo;
    float bb = bias[col];
#pragma unroll
    for (int r = 0; r < 4; ++r){
      int row = m0 + w * 16 + grp * 4 + r;
      out[(size_t)row * DH_ + col] = f2b(acc[nt][r] + bb);
    }
  }
}

// ---------------- V[8192][256] -> Vt bf16 [4][256][2048] ----------------
__global__ __launch_bounds__(256) void k_transpose_v(const ushort_t* __restrict__ V,
                                                     ushort_t* __restrict__ Vt){
  __shared__ ushort_t tile[32][33];
  int r0 = blockIdx.x * 32, c0 = blockIdx.y * 32;
  int t = threadIdx.x, tx = t & 31, ty = t >> 5;
#pragma unroll
  for (int i = 0; i < 4; ++i)
    tile[ty + i*8][tx] = V[(size_t)(r0 + ty + i*8) * DH_ + c0 + tx];
  __syncthreads();
  int b = r0 >> 11, s0 = r0 & (S_ - 1);
#pragma unroll
  for (int i = 0; i < 4; ++i)
    Vt[(size_t)(b * DH_ + c0 + ty + i*8) * S_ + s0 + tx] = tile[tx][ty + i*8];
}

// ---------------- flash attention: 1 block = 16 q rows, 8 waves key-split ----------------
__global__ __launch_bounds__(512) void k_attn(const ushort_t* __restrict__ Q,
                                              const ushort_t* __restrict__ K,
                                              const ushort_t* __restrict__ Vt,
                                              const float* __restrict__ padf,
                                              float* __restrict__ out){
  __shared__ __align__(16) ushort_t P[8][16][32];
  __shared__ float Osum[16][260];          // stride 260: 2-way bank alias max (free)
  __shared__ float ml[8][16][2];
  __shared__ float Linv[16];
  int blk = blockIdx.x;
  int b = blk & (B_ - 1);                  // b in low bits: one batch per XCD (L2 locality)
  int qt = (S_ / 16 - 1) - (blk >> 2);     // deepest q-tiles launch first
  int t = threadIdx.x;
  int lane = t & 63, w = t >> 6, lo = lane & 15, grp = lane >> 4;
  int qbase = qt * 16;
  const float NEG = -__builtin_inff();

  s16x8 aq[8];
#pragma unroll
  for (int d = 0; d < 8; ++d)
    aq[d] = *(const s16x8*)(Q + (size_t)(b * S_ + qbase + lo) * DH_ + d * 32 + grp * 8);

  f32x4 z4; z4[0] = z4[1] = z4[2] = z4[3] = 0.f;
  f32x4 o[16];
#pragma unroll
  for (int i = 0; i < 16; ++i) o[i] = z4;
  float m[4], l[4];
#pragma unroll
  for (int r = 0; r < 4; ++r){ m[r] = NEG; l[r] = 0.f; }

  int qhi = qbase + 15;
  int ntiles = (qhi >> 5) + 1;

  for (int kt = w; kt < ntiles; kt += 8){
    int k0 = kt * 32;
    f32x4 s[2];
#pragma unroll
    for (int h = 0; h < 2; ++h){
      int kb = k0 + h * 16;
      if (kb <= qhi){
        f32x4 acc = z4;
#pragma unroll
        for (int d = 0; d < 8; ++d){
          s16x8 bk = *(const s16x8*)(K + (size_t)(b * S_ + kb + lo) * DH_ + d * 32 + grp * 8);
          acc = MFMA16(aq[d], bk, acc);
        }
        int kcol = kb + lo;
        float pv = padf[b * S_ + kcol];
#pragma unroll
        for (int r = 0; r < 4; ++r){
          int q = qbase + grp * 4 + r;
          float v = acc[r] * 0.0625f + pv;     // 1/sqrt(256)
          s[h][r] = (kcol <= q) ? v : NEG;
        }
      } else {
#pragma unroll
        for (int r = 0; r < 4; ++r) s[h][r] = NEG;
      }
    }
    // online softmax; mexp guard: all-masked tiles must produce exact 0, not NaN
    float alpha[4];
    int need = 0;
#pragma unroll
    for (int r = 0; r < 4; ++r){
      float mr = fmaxf(s[0][r], s[1][r]);
      mr = fmaxf(mr, __shfl_xor(mr, 1));
      mr = fmaxf(mr, __shfl_xor(mr, 2));
      mr = fmaxf(mr, __shfl_xor(mr, 4));
      mr = fmaxf(mr, __shfl_xor(mr, 8));
      float mn = fmaxf(m[r], mr);
      float mexp = (mn == NEG) ? 0.f : mn;
      float al = __expf(m[r] - mexp);
      alpha[r] = al;
      float p0 = __expf(s[0][r] - mexp);
      float p1 = __expf(s[1][r] - mexp);
      s[0][r] = p0; s[1][r] = p1;
      float pr = p0 + p1;
      pr += __shfl_xor(pr, 1);
      pr += __shfl_xor(pr, 2);
      pr += __shfl_xor(pr, 4);
      pr += __shfl_xor(pr, 8);
      l[r] = l[r] * al + pr;
      need |= (mn > m[r]);
      m[r] = mn;
    }
    if (__any(need)){
#pragma unroll
      for (int i = 0; i < 16; ++i)
#pragma unroll
        for (int r = 0; r < 4; ++r) o[i][r] *= alpha[r];
    }
    // P -> LDS (bf16), re-fragment as MFMA A operand
#pragma unroll
    for (int h = 0; h < 2; ++h)
#pragma unroll
      for (int r = 0; r < 4; ++r)
        P[w][grp * 4 + r][h * 16 + lo] = f2b(s[h][r]);
    s16x8 pa = *(const s16x8*)(&P[w][lo][grp * 8]);
#pragma unroll
    for (int i = 0; i < 16; ++i){
      s16x8 vb = *(const s16x8*)(Vt + (size_t)(b * DH_ + i * 16 + lo) * S_ + k0 + grp * 8);
      o[i] = MFMA16(pa, vb, o[i]);
    }
  }

  // ---- cross-wave combine ----
  if (lo == 0){
#pragma unroll
    for (int r = 0; r < 4; ++r){ ml[w][grp * 4 + r][0] = m[r]; ml[w][grp * 4 + r][1] = l[r]; }
  }
  __syncthreads();
  float sc[4];
#pragma unroll
  for (int r = 0; r < 4; ++r){
    int row = grp * 4 + r;
    float Mx = NEG;
#pragma unroll
    for (int ww = 0; ww < 8; ++ww) Mx = fmaxf(Mx, ml[ww][row][0]);
    float Ls = 0.f;
#pragma unroll
    for (int ww = 0; ww < 8; ++ww) Ls += ml[ww][row][1] * __expf(ml[ww][row][0] - Mx);
    sc[r] = __expf(m[r] - Mx);
    if (w == 0 && lo == 0) Linv[row] = 1.0f / Ls;
  }
#pragma unroll
  for (int i = 0; i < 16; ++i)
#pragma unroll
    for (int r = 0; r < 4; ++r) o[i][r] *= sc[r];
  for (int ww = 0; ww < 8; ++ww){
    if (w == ww){
#pragma unroll
      for (int i = 0; i < 16; ++i)
#pragma unroll
        for (int r = 0; r < 4; ++r){
          float* p = &Osum[grp * 4 + r][i * 16 + lo];
          if (ww == 0) *p = o[i][r]; else *p += o[i][r];
        }
    }
    __syncthreads();
  }
  int row = t >> 5, sub = t & 31;
  float li = Linv[row];
  size_t obase = (size_t)(b * S_ + qbase + row) * DH_ + sub * 8;
#pragma unroll
  for (int j = 0; j < 8; ++j)
    out[obase + j] = Osum[row][sub * 8 + j] * li;
}

extern "C" void kernel_launch(void* const* d_in, const int* in_sizes, int n_in,
                              void* d_out, int out_size, void* d_ws, size_t ws_size,
                              hipStream_t stream){
  const float* x          = (const float*)d_in[0];
  // d_in[1] = causal_mask (semantics fixed: lower-triangular) — not read
  const unsigned char* pm = (const unsigned char*)d_in[2];
  const float* Wq = (const float*)d_in[3];
  const float* bQ = (const float*)d_in[4];
  const float* Wk = (const float*)d_in[5];
  const float* bK = (const float*)d_in[6];
  const float* Wv = (const float*)d_in[7];
  const float* bV = (const float*)d_in[8];
  float* out = (float*)d_out;

  char* ws = (char*)d_ws;
  ushort_t* xbf  = (ushort_t*)(ws);              // 33,554,432 B
  ushort_t* Wt   = (ushort_t*)(ws + 33554432);   //  3,145,728 B
  ushort_t* Qb   = (ushort_t*)(ws + 36700160);   //  4,194,304 B
  ushort_t* Kb   = (ushort_t*)(ws + 40894464);   //  4,194,304 B
  ushort_t* Vb   = (ushort_t*)(ws + 45088768);   //  4,194,304 B
  ushort_t* Vt   = (ushort_t*)(ws + 49283072);   //  4,194,304 B
  float*    padf = (float*)  (ws + 53477376);    //     32,768 B  (total ~53.5 MB)

  k_convert_x  <<<dim3(8192),       dim3(256), 0, stream>>>(x, xbf);
  k_transpose_w<<<dim3(64, 8, 3),   dim3(256), 0, stream>>>(Wq, Wk, Wv, Wt);
  k_prep_pad   <<<dim3(1),          dim3(256), 0, stream>>>(pm, padf);
  k_gemm_qkv   <<<dim3(128, 4, 3),  dim3(256), 0, stream>>>(xbf, Wt, bQ, bK, bV, Qb, Kb, Vb);
  k_transpose_v<<<dim3(256, 8),     dim3(256), 0, stream>>>(Vb, Vt);
  k_attn       <<<dim3(512),        dim3(512), 0, stream>>>(Qb, Kb, Vt, padf, out);
}

// Round 3
// 266.776 us; speedup vs baseline: 1.8227x; 1.1261x over previous
//
#include <hip/hip_runtime.h>
#include <stdint.h>

typedef float  f32x4  __attribute__((ext_vector_type(4)));
typedef short  s16x8  __attribute__((ext_vector_type(8)));
typedef unsigned int u32x4 __attribute__((ext_vector_type(4)));
typedef unsigned short ushort_t;
typedef unsigned int uint_t;

#define B_  4
#define S_  2048
#define E_  2048
#define DH_ 256

#define MFMA16(a,b,c) __builtin_amdgcn_mfma_f32_16x16x32_bf16((a),(b),(c),0,0,0)

#define GL16(gp, lp) __builtin_amdgcn_global_load_lds( \
    (const __attribute__((address_space(1))) unsigned int*)(gp), \
    (__attribute__((address_space(3))) unsigned int*)(lp), 16, 0, 0)

__device__ __forceinline__ ushort_t f2b(float f){
  unsigned u = __builtin_bit_cast(unsigned, f);
  u += 0x7fffu + ((u >> 16) & 1u);   // RNE
  return (ushort_t)(u >> 16);
}

// ---------------- x fp32 -> bf16 ----------------
__global__ __launch_bounds__(256) void k_convert_x(const float* __restrict__ x,
                                                   ushort_t* __restrict__ xbf){
  size_t i = ((size_t)blockIdx.x * 256 + threadIdx.x) * 8;
  f32x4 a = *(const f32x4*)(x + i);
  f32x4 b = *(const f32x4*)(x + i + 4);
  union { ushort_t us[8]; u32x4 v; } u;
#pragma unroll
  for (int j = 0; j < 4; ++j){ u.us[j] = f2b(a[j]); u.us[4+j] = f2b(b[j]); }
  *(u32x4*)(xbf + i) = u.v;
}

// ---------------- W[2048][256] -> Wt bf16 [3][256][2048] ----------------
__global__ __launch_bounds__(256) void k_transpose_w(const float* __restrict__ Wq,
                                                     const float* __restrict__ Wk,
                                                     const float* __restrict__ Wv,
                                                     ushort_t* __restrict__ Wt){
  __shared__ ushort_t tile[32][33];
  int z = blockIdx.z;
  const float* W = (z == 0) ? Wq : ((z == 1) ? Wk : Wv);
  int k0 = blockIdx.x * 32, n0 = blockIdx.y * 32;
  int t = threadIdx.x, tx = t & 31, ty = t >> 5;
#pragma unroll
  for (int i = 0; i < 4; ++i)
    tile[ty + i*8][tx] = f2b(W[(size_t)(k0 + ty + i*8) * DH_ + n0 + tx]);
  __syncthreads();
#pragma unroll
  for (int i = 0; i < 4; ++i)
    Wt[(size_t)z * DH_ * E_ + (size_t)(n0 + ty + i*8) * E_ + k0 + tx] = tile[tx][ty + i*8];
}

// ------- padding mask (bool-bytes OR int32) -> u32 bitmask per 32-key tile -------
__global__ __launch_bounds__(256) void k_prep_pad(const unsigned char* __restrict__ pm,
                                                  uint_t* __restrict__ padbits){
  const int n = B_ * S_;
  int any = 0;
  for (int i = threadIdx.x; i < n; i += 256)
    if ((i & 3) && pm[i]) any = 1;            // nonzero at i%4!=0 => bool layout
  int isb = __syncthreads_or(any);
  int t = threadIdx.x;                         // 256 threads = 4 batches x 64 tiles
  uint_t bits = 0;
  int base = (t >> 6) * S_ + (t & 63) * 32;
#pragma unroll
  for (int j = 0; j < 32; ++j){
    size_t idx = base + j;
    unsigned char v = isb ? pm[idx] : pm[idx * 4];
    bits |= (v ? 1u : 0u) << j;
  }
  padbits[t] = bits;
}

// -------- QKV projection GEMM: 128x64 tile, BK=64, global_load_lds, swz reads --------
__global__ __launch_bounds__(256) void k_gemm_qkv(const ushort_t* __restrict__ xbf,
                                                  const ushort_t* __restrict__ Wt,
                                                  const float* __restrict__ bQ,
                                                  const float* __restrict__ bK,
                                                  const float* __restrict__ bV,
                                                  ushort_t* __restrict__ Qo,
                                                  ushort_t* __restrict__ Ko,
                                                  ushort_t* __restrict__ Vo){
  __shared__ __align__(16) ushort_t Al[128 * 64];  // linear [row][k], src pre-swizzled
  __shared__ __align__(16) ushort_t Bl[64 * 64];
  int z = blockIdx.z;
  const ushort_t* W = Wt + (size_t)z * DH_ * E_;
  const float* bias = (z == 0) ? bQ : ((z == 1) ? bK : bV);
  ushort_t* out = (z == 0) ? Qo : ((z == 1) ? Ko : Vo);
  int m0 = blockIdx.x * 128, n0 = blockIdx.y * 64;
  int t = threadIdx.x;
  int lane = t & 63, w = t >> 6, lo = lane & 15, grp = lane >> 4;
  int wm = w >> 1, wn = w & 1;                   // 2x2 waves, each 64x32 output
  int rA = t >> 3;                                // staging row 0..31 per round
  int jsw = ((t & 7) ^ (rA & 7)) * 8;             // inverse-swizzled source chunk

  f32x4 z4; z4[0] = z4[1] = z4[2] = z4[3] = 0.f;
  f32x4 acc[4][2];
#pragma unroll
  for (int mt = 0; mt < 4; ++mt){ acc[mt][0] = z4; acc[mt][1] = z4; }

  char* lA = (char*)Al + w * 1024;
  char* lB = (char*)Bl + w * 1024;

  for (int k0 = 0; k0 < E_; k0 += 64){
    __syncthreads();
    const ushort_t* gA = xbf + (size_t)(m0 + rA) * E_ + k0 + jsw;
    const ushort_t* gB = W   + (size_t)(n0 + rA) * E_ + k0 + jsw;
#pragma unroll
    for (int i = 0; i < 4; ++i)
      GL16(gA + (size_t)i * 32 * E_, lA + i * 4096);
#pragma unroll
    for (int i = 0; i < 2; ++i)
      GL16(gB + (size_t)i * 32 * E_, lB + i * 4096);
    __syncthreads();   // compiler inserts vmcnt(0) drain before barrier
#pragma unroll
    for (int kk = 0; kk < 2; ++kk){
      s16x8 av[4], bv[2];
#pragma unroll
      for (int mt = 0; mt < 4; ++mt){
        int row = wm * 64 + mt * 16 + lo;
        av[mt] = *(const s16x8*)((char*)Al + ((row * 128 + kk * 64 + grp * 16) ^ ((row & 7) << 4)));
      }
#pragma unroll
      for (int nt = 0; nt < 2; ++nt){
        int row = wn * 32 + nt * 16 + lo;
        bv[nt] = *(const s16x8*)((char*)Bl + ((row * 128 + kk * 64 + grp * 16) ^ ((row & 7) << 4)));
      }
#pragma unroll
      for (int mt = 0; mt < 4; ++mt)
#pragma unroll
        for (int nt = 0; nt < 2; ++nt)
          acc[mt][nt] = MFMA16(av[mt], bv[nt], acc[mt][nt]);
    }
  }
#pragma unroll
  for (int nt = 0; nt < 2; ++nt){
    int col = n0 + wn * 32 + nt * 16 + lo;
    float bb = bias[col];
#pragma unroll
    for (int mt = 0; mt < 4; ++mt)
#pragma unroll
      for (int r = 0; r < 4; ++r){
        int row = m0 + wm * 64 + mt * 16 + grp * 4 + r;
        out[(size_t)row * DH_ + col] = f2b(acc[mt][nt][r] + bb);
      }
  }
}

// ---------------- V[8192][256] -> Vt bf16 [4][256][2048] ----------------
__global__ __launch_bounds__(256) void k_transpose_v(const ushort_t* __restrict__ V,
                                                     ushort_t* __restrict__ Vt){
  __shared__ ushort_t tile[32][33];
  int r0 = blockIdx.x * 32, c0 = blockIdx.y * 32;
  int t = threadIdx.x, tx = t & 31, ty = t >> 5;
#pragma unroll
  for (int i = 0; i < 4; ++i)
    tile[ty + i*8][tx] = V[(size_t)(r0 + ty + i*8) * DH_ + c0 + tx];
  __syncthreads();
  int b = r0 >> 11, s0 = r0 & (S_ - 1);
#pragma unroll
  for (int i = 0; i < 4; ++i)
    Vt[(size_t)(b * DH_ + c0 + ty + i*8) * S_ + s0 + tx] = tile[tx][ty + i*8];
}

// ------- flash attention: 1 block = 16 q rows, 8 waves key-split, KVBLK=64 -------
// Swapped QK^T: mfma(K,Q) -> lane holds scores for q = lane&15, keys on (grp,reg).
__global__ __launch_bounds__(512) void k_attn(const ushort_t* __restrict__ Q,
                                              const ushort_t* __restrict__ K,
                                              const ushort_t* __restrict__ Vt,
                                              const uint_t* __restrict__ padbits,
                                              float* __restrict__ out){
  __shared__ __align__(16) ushort_t P[8][16][72];  // 144B row stride (16B-aligned)
  __shared__ float Osum[16][260];
  __shared__ float ml[8][16][2];
  __shared__ float Linv[16];
  int blk = blockIdx.x;
  int b = blk & (B_ - 1);                  // batch in low bits: KV L2 locality per XCD
  int qt = (S_ / 16 - 1) - (blk >> 2);     // deepest q-tiles launch first
  int t = threadIdx.x;
  int lane = t & 63, w = t >> 6, lo = lane & 15, grp = lane >> 4;
  int qbase = qt * 16;
  const float NEG = -__builtin_inff();
  const float MSENT = -1e30f;              // finite sentinel: no NaN/inf paths

  // Q as B-operand fragments
  s16x8 aq[8];
#pragma unroll
  for (int d = 0; d < 8; ++d)
    aq[d] = *(const s16x8*)(Q + (size_t)(b * S_ + qbase + lo) * DH_ + d * 32 + grp * 8);

  f32x4 z4; z4[0] = z4[1] = z4[2] = z4[3] = 0.f;
  f32x4 o[16];
#pragma unroll
  for (int i = 0; i < 16; ++i) o[i] = z4;
  float m_lo = MSENT, l_lo = 0.f;

  int qhi = qbase + 15;
  int nt64 = (qhi >> 6) + 1;

  for (int kt = w; kt < nt64; kt += 8){
    int k0 = kt * 64;
    bool full = (k0 + 63 <= qbase);        // wave-uniform: no causal masking needed
    f32x4 sc[4];
#pragma unroll
    for (int h = 0; h < 4; ++h) sc[h] = z4;
#pragma unroll
    for (int d = 0; d < 8; ++d){
#pragma unroll
      for (int h = 0; h < 4; ++h){
        s16x8 kf = *(const s16x8*)(K + (size_t)(b * S_ + k0 + h * 16 + lo) * DH_ + d * 32 + grp * 8);
        sc[h] = MFMA16(kf, aq[d], sc[h]);  // swapped: A=K(rows=keys), B=Q(cols=q)
      }
    }
    // scale + padding bitmask
    uint_t pb0 = padbits[b * 64 + kt * 2];
    uint_t pb1 = padbits[b * 64 + kt * 2 + 1];
#pragma unroll
    for (int h = 0; h < 4; ++h){
      uint_t bg = ((h < 2 ? pb0 : pb1) >> ((h & 1) * 16)) >> (4 * grp);
#pragma unroll
      for (int r = 0; r < 4; ++r){
        float v = sc[h][r] * 0.0625f;      // 1/sqrt(256)
        sc[h][r] = ((bg >> r) & 1) ? NEG : v;
      }
    }
    if (!full){                            // causal: key = k0+h*16+4*grp+r vs q = qbase+lo
#pragma unroll
      for (int h = 0; h < 4; ++h)
#pragma unroll
        for (int r = 0; r < 4; ++r)
          if (k0 + h * 16 + 4 * grp + r > qbase + lo) sc[h][r] = NEG;
    }
    // tile max (in-lane + 2 shfl across the 4 groups sharing lo)
    float mt0 = fmaxf(fmaxf(sc[0][0], sc[0][1]), fmaxf(sc[0][2], sc[0][3]));
    float mt1 = fmaxf(fmaxf(sc[1][0], sc[1][1]), fmaxf(sc[1][2], sc[1][3]));
    float mt2 = fmaxf(fmaxf(sc[2][0], sc[2][1]), fmaxf(sc[2][2], sc[2][3]));
    float mt3 = fmaxf(fmaxf(sc[3][0], sc[3][1]), fmaxf(sc[3][2], sc[3][3]));
    float mt = fmaxf(fmaxf(mt0, mt1), fmaxf(mt2, mt3));
    mt = fmaxf(mt, __shfl_xor(mt, 16));
    mt = fmaxf(mt, __shfl_xor(mt, 32));
    // deferred rescale (THR=8): rare; wave-uniform branch
    if (__any(mt > m_lo + 8.f)){
      float mn = fmaxf(m_lo, mt);
      float al = __expf(m_lo - mn);        // m_lo=-1e30 -> 0 (flushes nothing real)
      m_lo = mn;
      l_lo *= al;
      float a0 = __shfl(al, 4 * grp + 0);
      float a1 = __shfl(al, 4 * grp + 1);
      float a2 = __shfl(al, 4 * grp + 2);
      float a3 = __shfl(al, 4 * grp + 3);
#pragma unroll
      for (int i = 0; i < 16; ++i){
        o[i][0] *= a0; o[i][1] *= a1; o[i][2] *= a2; o[i][3] *= a3;
      }
    }
    // p = exp(s - m)  (bounded by e^8), row-sum via in-lane + 2 shfl
    float ls = 0.f;
#pragma unroll
    for (int h = 0; h < 4; ++h)
#pragma unroll
      for (int r = 0; r < 4; ++r){
        float p = __expf(sc[h][r] - m_lo);
        sc[h][r] = p;
        ls += p;
      }
    ls += __shfl_xor(ls, 16);
    ls += __shfl_xor(ls, 32);
    l_lo += ls;
    // P -> LDS bf16 (row = q = lo), re-fragment as PV A-operand
    char* prow = (char*)&P[w][lo][0];
#pragma unroll
    for (int h = 0; h < 4; ++h){
      uint_t u0 = (uint_t)f2b(sc[h][0]) | ((uint_t)f2b(sc[h][1]) << 16);
      uint_t u1 = (uint_t)f2b(sc[h][2]) | ((uint_t)f2b(sc[h][3]) << 16);
      *(uint_t*)(prow + h * 32 + grp * 8)     = u0;   // keys h*16+4g+{0,1}
      *(uint_t*)(prow + h * 32 + grp * 8 + 4) = u1;   // keys h*16+4g+{2,3}
    }
    s16x8 pa0 = *(const s16x8*)(prow + grp * 16);        // keys grp*8..+7
    s16x8 pa1 = *(const s16x8*)(prow + 64 + grp * 16);   // keys 32+grp*8..+7
#pragma unroll
    for (int i = 0; i < 16; ++i){
      s16x8 v0 = *(const s16x8*)(Vt + (size_t)(b * DH_ + i * 16 + lo) * S_ + k0 + grp * 8);
      s16x8 v1 = *(const s16x8*)(Vt + (size_t)(b * DH_ + i * 16 + lo) * S_ + k0 + 32 + grp * 8);
      o[i] = MFMA16(pa0, v0, o[i]);
      o[i] = MFMA16(pa1, v1, o[i]);
    }
  }

  // convert m,l to output layout (q = grp*4+r)
  float mo[4], lo_[4];
#pragma unroll
  for (int r = 0; r < 4; ++r){
    mo[r]  = __shfl(m_lo, 4 * grp + r);
    lo_[r] = __shfl(l_lo, 4 * grp + r);
  }

  // ---- cross-wave combine ----
  if (lo == 0){
#pragma unroll
    for (int r = 0; r < 4; ++r){ ml[w][grp * 4 + r][0] = mo[r]; ml[w][grp * 4 + r][1] = lo_[r]; }
  }
  __syncthreads();
  float sc2[4];
#pragma unroll
  for (int r = 0; r < 4; ++r){
    int row = grp * 4 + r;
    float Mx = MSENT;
#pragma unroll
    for (int ww = 0; ww < 8; ++ww) Mx = fmaxf(Mx, ml[ww][row][0]);
    float Ls = 0.f;
#pragma unroll
    for (int ww = 0; ww < 8; ++ww) Ls += ml[ww][row][1] * __expf(ml[ww][row][0] - Mx);
    sc2[r] = __expf(mo[r] - Mx);
    if (w == 0 && lo == 0) Linv[row] = 1.0f / Ls;
  }
#pragma unroll
  for (int i = 0; i < 16; ++i)
#pragma unroll
    for (int r = 0; r < 4; ++r) o[i][r] *= sc2[r];
  for (int ww = 0; ww < 8; ++ww){
    if (w == ww){
#pragma unroll
      for (int i = 0; i < 16; ++i)
#pragma unroll
        for (int r = 0; r < 4; ++r){
          float* p = &Osum[grp * 4 + r][i * 16 + lo];
          if (ww == 0) *p = o[i][r]; else *p += o[i][r];
        }
    }
    __syncthreads();
  }
  int row = t >> 5, sub = t & 31;
  float li = Linv[row];
  size_t obase = (size_t)(b * S_ + qbase + row) * DH_ + sub * 8;
#pragma unroll
  for (int j = 0; j < 8; ++j)
    out[obase + j] = Osum[row][sub * 8 + j] * li;
}

extern "C" void kernel_launch(void* const* d_in, const int* in_sizes, int n_in,
                              void* d_out, int out_size, void* d_ws, size_t ws_size,
                              hipStream_t stream){
  const float* x          = (const float*)d_in[0];
  // d_in[1] = causal_mask (semantics fixed: lower-triangular) — not read
  const unsigned char* pm = (const unsigned char*)d_in[2];
  const float* Wq = (const float*)d_in[3];
  const float* bQ = (const float*)d_in[4];
  const float* Wk = (const float*)d_in[5];
  const float* bK = (const float*)d_in[6];
  const float* Wv = (const float*)d_in[7];
  const float* bV = (const float*)d_in[8];
  float* out = (float*)d_out;

  char* ws = (char*)d_ws;
  ushort_t* xbf  = (ushort_t*)(ws);              // 33,554,432 B
  ushort_t* Wt   = (ushort_t*)(ws + 33554432);   //  3,145,728 B
  ushort_t* Qb   = (ushort_t*)(ws + 36700160);   //  4,194,304 B
  ushort_t* Kb   = (ushort_t*)(ws + 40894464);   //  4,194,304 B
  ushort_t* Vb   = (ushort_t*)(ws + 45088768);   //  4,194,304 B
  ushort_t* Vt   = (ushort_t*)(ws + 49283072);   //  4,194,304 B
  uint_t*   padbits = (uint_t*)(ws + 53477376);  //      1,024 B

  k_convert_x  <<<dim3(8192),       dim3(256), 0, stream>>>(x, xbf);
  k_transpose_w<<<dim3(64, 8, 3),   dim3(256), 0, stream>>>(Wq, Wk, Wv, Wt);
  k_prep_pad   <<<dim3(1),          dim3(256), 0, stream>>>(pm, padbits);
  k_gemm_qkv   <<<dim3(64, 4, 3),   dim3(256), 0, stream>>>(xbf, Wt, bQ, bK, bV, Qb, Kb, Vb);
  k_transpose_v<<<dim3(256, 8),     dim3(256), 0, stream>>>(Vb, Vt);
  k_attn       <<<dim3(512),        dim3(512), 0, stream>>>(Qb, Kb, Vt, padbits, out);
}